// Round 3
// baseline (240.619 us; speedup 1.0000x reference)
//
#include <hip/hip_runtime.h>

// Xonv2D: location-dependent 3x3 conv.
//   x:       (B=4, CIN=16, H=128, W=128)  fp32   -- 4 MB, L2-resident
//   weights: (H, W, COUT=16, CIN=16, 3, 3) fp32  -- 151 MB, the traffic driver
//   bias:    (H, W, COUT) fp32
//   out:     (B, COUT, H, W) fp32
//
// V8: decouple x from the weight stream; prefetch is always the NEWEST vmem.
//  V6/V7 diagnosis (rocprof): 29,000 cy/site, VALUBusy 8.5%, supply 1.55TB/s
//  -- waves sit in vmcnt waits. Root cause: vmcnt retires IN ORDER, so the
//  compiler's wait for ANY x-load drains the (older) weight prefetch; the
//  9-load burst is in flight ~3% of the time. Fix: per site, issue order is
//    [w-frag ds_read -> regs] [3 coop x-loads + bias] [9-load w prefetch]
//    [vmcnt(9): x ready, prefetch still flying] [LDS-only compute] [store]
//  The prefetch is the newest op at every wait point, so it flies across the
//  whole FMA phase and the next site's load-issue phase (~90% duty).
//  The 48 per-lane x loads (16 o-lanes duplicated identical x!) collapse to
//  3 vector loads for the site's 192 unique float4s, published to a 3KB LDS
//  slot and consumed via broadcast ds_read (lgkmcnt -- never drains vmcnt).
//  Single 9KB weight buffer/wave (frag extracted to regs before the DMA
//  reuses it; lgkmcnt(0) orders read-complete before DMA issue -- no race).
//  12KB LDS/wave -> 48KB/block -> 3 blocks/CU = 12 waves/CU (was 8).
//  ~100KB weight bytes in flight per CU vs ~2.5KB effective before.
//
// Kept: coalesced weight DMA order (lane l takes f4 j*64+l, linear LDS dest),
// per-lane (o,g) 36-float fragment, wave-uniform w-border slow path, per-lane
// h-border predication (now baked into the x slot as zeros), XCD banding,
// butterfly reduce, single store per lane. No barriers anywhere: waves stay
// fully independent.

#define HWD   128
#define CIND  16
#define COUTD 16
#define BATCH 4
#define SPW   4     // sites per wave (consecutive, same row: 4 | 128)
#define WPB   4     // waves per block

typedef float f4  __attribute__((ext_vector_type(4)));
typedef float f4u __attribute__((ext_vector_type(4), aligned(4)));

// async DMA: 16B per lane, LDS dest = wave-uniform base + lane*16 (linear).
__device__ __forceinline__ void gload_lds16(const f4* gsrc, f4* ldst) {
    __builtin_amdgcn_global_load_lds(
        (const __attribute__((address_space(1))) unsigned int*)gsrc,
        (__attribute__((address_space(3))) unsigned int*)ldst,
        16, 0, 0);
}

__global__ __launch_bounds__(256) void xonv2d_kernel(
    const float* __restrict__ x,
    const float* __restrict__ wts,
    const float* __restrict__ bias,
    float* __restrict__ out)
{
    __shared__ f4 wbuf[WPB][576];    // 9216 B/wave: single weight buffer
    __shared__ f4 xslot[WPB][192];   // 3072 B/wave: site x window, zero-padded

    const int lane = threadIdx.x & 63;
    const int wave = threadIdx.x >> 6;

    // XCD banding: XCD k = blockIdx%8 handles sites [k*2048, (k+1)*2048).
    const int xcd = blockIdx.x & 7;
    const int idx = blockIdx.x >> 3;                    // 0..127 within band
    const int site0 = xcd * 2048 + (idx * WPB + wave) * SPW;

    const int o  = lane & 15;    // output channel
    const int g  = lane >> 4;    // channel group: c in [4g, 4g+4)
    const int c0 = g * 4;

    // x-stage decode: element S = lane + 64*j (S < 192) holds the f4 window
    // (cols w-1..w+2) of batch b = S/48, channel c = (S%48)/3, row r = S%3.
    // Slot index == S since (b*16+c)*3 + r == S.
    int sb[3], sc[3], sr[3];
    #pragma unroll
    for (int j = 0; j < 3; ++j) {
        const int S = lane + 64 * j;
        sb[j] = S / 48;
        const int u = S - sb[j] * 48;
        sc[j] = u / 3;
        sr[j] = u - sc[j] * 3;
    }

    // ---- prologue: DMA site0's weights (the only vmem in flight) ----
    {
        const f4* gw = (const f4*)wts + (size_t)site0 * 576;
        #pragma unroll
        for (int j = 0; j < 9; ++j)
            gload_lds16(gw + j * 64 + lane, &wbuf[wave][j * 64]);
    }

    #pragma unroll 1
    for (int s = 0; s < SPW; ++s) {
        const int site = site0 + s;
        const int h = site >> 7;
        const int w = site & 127;

        // A: this site's weight DMA landed. (s>0: the single newer op is
        // last iteration's store; in-order retirement makes vmcnt(1) exact.)
        if (s == 0) asm volatile("s_waitcnt vmcnt(0)" ::: "memory");
        else        asm volatile("s_waitcnt vmcnt(1)" ::: "memory");
        __builtin_amdgcn_sched_barrier(0);

        // B: weight fragment -> regs; after lgkmcnt(0) the buffer is free.
        f4 wv[9];
        {
            const f4* lp = &wbuf[wave][o * 36 + g * 9];
            #pragma unroll
            for (int j = 0; j < 9; ++j) wv[j] = lp[j];   // ds_read_b128
        }
        asm volatile("s_waitcnt lgkmcnt(0)" ::: "memory");
        __builtin_amdgcn_sched_barrier(0);
        const float* wf = (const float*)wv;

        // C: cooperative x stage (3 f4/lane = site's 192 unique f4) + bias.
        //    Issued BEFORE the prefetch so their waits never drain it.
        f4 xr[3];
        const bool wfast = (w >= 1) && (w <= HWD - 3);
        #pragma unroll
        for (int j = 0; j < 3; ++j) {
            const int hy  = h + sr[j] - 1;
            const bool okh = (unsigned)hy < (unsigned)HWD;
            const int hyc = okh ? hy : 0;
            const float* xb = x + ((size_t)(sb[j] * CIND + sc[j]) * HWD + hyc) * HWD;
            if (wfast) {
                f4 v = *(const f4u*)(xb + (w - 1));
                xr[j] = okh ? v : (f4){0.f, 0.f, 0.f, 0.f};
            } else {
                // w in {0,126,127}: wave-uniform slow path, per-col predication
                f4 v;
                #pragma unroll
                for (int jj = 0; jj < 4; ++jj) {
                    const int cw = w - 1 + jj;
                    const bool ok = okh && ((unsigned)cw < (unsigned)HWD);
                    v[jj] = ok ? xb[cw] : 0.f;
                }
                xr[j] = v;
            }
        }
        const float bv = bias[(size_t)site * COUTD + o];
        __builtin_amdgcn_sched_barrier(0);

        // D: prefetch next site's weights into the SAME buffer (frag is in
        //    regs; lgkmcnt(0) above ordered the reads before this DMA).
        if (s + 1 < SPW) {
            const f4* gw = (const f4*)wts + (size_t)(site + 1) * 576;
            #pragma unroll
            for (int j = 0; j < 9; ++j)
                gload_lds16(gw + j * 64 + lane, &wbuf[wave][j * 64]);
        }
        __builtin_amdgcn_sched_barrier(0);

        // E: x+bias ready; the 9 newest (weight prefetch) stay in flight
        //    across the entire compute phase and the next site's loads.
        if (s + 1 < SPW) asm volatile("s_waitcnt vmcnt(9)" ::: "memory");
        else             asm volatile("s_waitcnt vmcnt(0)" ::: "memory");
        __builtin_amdgcn_sched_barrier(0);

        // F: publish x to LDS, compute entirely from LDS (lgkm only).
        #pragma unroll
        for (int j = 0; j < 3; ++j)
            xslot[wave][lane + 64 * j] = xr[j];          // ds_write_b128

        float acc[BATCH] = {0.f, 0.f, 0.f, 0.f};
        #pragma unroll
        for (int cc = 0; cc < 4; ++cc) {
            #pragma unroll
            for (int b = 0; b < BATCH; ++b) {
                // 16 o-lanes read the same address: LDS broadcast, free.
                const f4* xp = &xslot[wave][(b * CIND + c0 + cc) * 3];
                const f4 r0 = xp[0];
                const f4 r1 = xp[1];
                const f4 r2 = xp[2];
                const float* wr = wf + cc * 9;
                acc[b] = fmaf(r0.x, wr[0], acc[b]);
                acc[b] = fmaf(r0.y, wr[1], acc[b]);
                acc[b] = fmaf(r0.z, wr[2], acc[b]);
                acc[b] = fmaf(r1.x, wr[3], acc[b]);
                acc[b] = fmaf(r1.y, wr[4], acc[b]);
                acc[b] = fmaf(r1.z, wr[5], acc[b]);
                acc[b] = fmaf(r2.x, wr[6], acc[b]);
                acc[b] = fmaf(r2.y, wr[7], acc[b]);
                acc[b] = fmaf(r2.z, wr[8], acc[b]);
            }
        }

        // ---- butterfly reduce over the 4 c-groups ----
        float r[BATCH];
        #pragma unroll
        for (int b = 0; b < BATCH; ++b) {
            float v = acc[b];
            v += __shfl_xor(v, 32);
            v += __shfl_xor(v, 16);
            r[b] = v;
        }

        // lane (g,o) stores batch b = g: one store, all 64 lanes active
        const float vout = (g == 0) ? r[0] : (g == 1) ? r[1] : (g == 2) ? r[2] : r[3];
        out[((size_t)(g * COUTD + o)) * (HWD * HWD) + h * HWD + w] = vout + bv;
    }
}

extern "C" void kernel_launch(void* const* d_in, const int* in_sizes, int n_in,
                              void* d_out, int out_size, void* d_ws, size_t ws_size,
                              hipStream_t stream) {
    const float* x    = (const float*)d_in[0];
    const float* wts  = (const float*)d_in[1];
    const float* bias = (const float*)d_in[2];
    float* out = (float*)d_out;

    // 16384 sites / (4 waves * 4 sites) = 1024 blocks of 256 threads.
    // 48KB LDS -> 3 blocks/CU = 12 waves/CU; 768 resident + fast turnover.
    const int blocks = (HWD * HWD) / (WPB * SPW);
    xonv2d_kernel<<<blocks, WPB * 64, 0, stream>>>(x, wts, bias, out);
}

// Round 4
// 233.410 us; speedup vs baseline: 1.0309x; 1.0309x over previous
//
#include <hip/hip_runtime.h>

// Xonv2D: location-dependent 3x3 conv.
//   x:       (B=4, CIN=16, H=128, W=128)  fp32   -- 4 MB, L2-resident
//   weights: (H, W, COUT=16, CIN=16, 3, 3) fp32  -- 151 MB, the traffic driver
//   bias:    (H, W, COUT) fp32
//   out:     (B, COUT, H, W) fp32
//
// V9: V8's schedule, but weights staged through REGISTERS, not LDS-DMA.
//  V8 diagnosis: correct issue order + counted waits, occupancy 21%, yet
//  ~40Kcy per 9-load global_load_lds burst => ~370cy serialized service per
//  DMA instruction (~2.7 B/cy/CU == the measured 1.6 TB/s). The LDS-DMA
//  path does not pipeline per CU. Evidence: V5 (plain per-lane loads, worse
//  schedule) was faster; fills sustain 28 B/cy/CU; m13 copy = 10 B/cy/CU
//  with plain dwordx4. So V9 removes global_load_lds entirely:
//    depth-2 register staging stA/stB (9 f4 each). Per site s:
//      [ds_write st(s) -> wave transpose buffer]   (compiler-counted vmcnt
//       wait on the staged regs: keeps the newer in-flight burst alive)
//      [ds_read (o,g) 36-float fragment]
//      [3 coop x-loads + bias]                     (before the burst!)
//      [burst: site s+2 weights -> same reg buffer] (newest vmem: survives
//       the x-wait vmcnt(9) and the whole next iteration)
//      [LDS-only compute, butterfly, store]
//  All waits are the compiler's own counted vmcnt (program order pinned
//  with sched_barrier(0)); burst coverage = one full iteration.
//
// Kept from V8 (verified): coop-x stage (wave's 192 unique f4 in 3 loads,
// LDS broadcast consumption -- compute phase is vmem-free), per-lane (o,g)
// fragment layout, wave-uniform w-border path + h clamp-and-zero, XCD
// banding, butterfly reduce, single store. No barriers: waves independent.

#define HWD   128
#define CIND  16
#define COUTD 16
#define BATCH 4
#define SPW   4     // sites per wave (consecutive, 4 | 128 so same row)
#define WPB   4     // waves per block

typedef float f4  __attribute__((ext_vector_type(4)));
typedef float f4u __attribute__((ext_vector_type(4), aligned(4)));

struct WaveCtx {
    const float* x;
    const float* bias;
    float*       out;
    const f4*    gw0;      // weight base for site0 (f4 units)
    f4*          wbuf;     // wave's 576-f4 transpose buffer
    f4*          xslot;    // wave's 192-f4 x window slot
    int site0, lane, o, g;
    int sb[3], sc[3], sr[3];
};

__device__ __forceinline__ void site_iter(const WaveCtx& W, const int s,
                                          f4 (&st)[9], const bool burst)
{
    const int site = W.site0 + s;
    const int h = site >> 7;
    const int w = site & 127;

    // ---- staged regs -> LDS transpose buffer; fragment -> regs ----
    // (compiler inserts a counted vmcnt here for st's loads; anything
    //  newer -- the previous iteration's burst is OLDER, so it's exact)
    #pragma unroll
    for (int j = 0; j < 9; ++j)
        W.wbuf[j * 64 + W.lane] = st[j];             // ds_write_b128
    f4 wv[9];
    {
        const f4* lp = W.wbuf + (W.o * 36 + W.g * 9);
        #pragma unroll
        for (int j = 0; j < 9; ++j) wv[j] = lp[j];   // ds_read_b128
    }
    const float* wf = (const float*)wv;
    __builtin_amdgcn_sched_barrier(0);

    // ---- coop x stage: 3 f4/lane = the site's 192 unique f4, + bias.
    //      Issued BEFORE the burst so x-waits never drain it. ----
    f4 xr[3];
    const bool wfast = (w >= 1) && (w <= HWD - 3);
    #pragma unroll
    for (int j = 0; j < 3; ++j) {
        const int hy   = h + W.sr[j] - 1;
        const bool okh = (unsigned)hy < (unsigned)HWD;
        const int hyc  = okh ? hy : 0;
        const float* xb = W.x + ((size_t)(W.sb[j] * CIND + W.sc[j]) * HWD + hyc) * HWD;
        if (wfast) {
            f4 v = *(const f4u*)(xb + (w - 1));
            xr[j] = okh ? v : (f4){0.f, 0.f, 0.f, 0.f};
        } else {
            f4 v;
            #pragma unroll
            for (int jj = 0; jj < 4; ++jj) {
                const int cw = w - 1 + jj;
                const bool ok = okh && ((unsigned)cw < (unsigned)HWD);
                v[jj] = ok ? xb[cw] : 0.f;
            }
            xr[j] = v;
        }
    }
    const float bv = W.bias[(size_t)site * COUTD + W.o];
    __builtin_amdgcn_sched_barrier(0);

    // ---- depth-2 burst: site+2 weights into the just-freed reg buffer.
    //      Newest vmem at every subsequent wait point. ----
    if (burst) {
        const f4* gw = W.gw0 + (size_t)(s + 2) * 576;
        #pragma unroll
        for (int j = 0; j < 9; ++j)
            st[j] = gw[j * 64 + W.lane];             // global_load_dwordx4
    }
    __builtin_amdgcn_sched_barrier(0);

    // ---- publish x, compute entirely from LDS (lgkm only) ----
    #pragma unroll
    for (int j = 0; j < 3; ++j)
        W.xslot[W.lane + 64 * j] = xr[j];            // ds_write_b128

    const int c0 = W.g * 4;
    float acc[BATCH] = {0.f, 0.f, 0.f, 0.f};
    #pragma unroll
    for (int cc = 0; cc < 4; ++cc) {
        #pragma unroll
        for (int b = 0; b < BATCH; ++b) {
            // 16 o-lanes read the same address: LDS broadcast, free.
            const f4* xp = &W.xslot[(b * CIND + c0 + cc) * 3];
            const f4 r0 = xp[0];
            const f4 r1 = xp[1];
            const f4 r2 = xp[2];
            const float* wr = wf + cc * 9;
            acc[b] = fmaf(r0.x, wr[0], acc[b]);
            acc[b] = fmaf(r0.y, wr[1], acc[b]);
            acc[b] = fmaf(r0.z, wr[2], acc[b]);
            acc[b] = fmaf(r1.x, wr[3], acc[b]);
            acc[b] = fmaf(r1.y, wr[4], acc[b]);
            acc[b] = fmaf(r1.z, wr[5], acc[b]);
            acc[b] = fmaf(r2.x, wr[6], acc[b]);
            acc[b] = fmaf(r2.y, wr[7], acc[b]);
            acc[b] = fmaf(r2.z, wr[8], acc[b]);
        }
    }

    // ---- butterfly reduce over the 4 c-groups ----
    float r[BATCH];
    #pragma unroll
    for (int b = 0; b < BATCH; ++b) {
        float v = acc[b];
        v += __shfl_xor(v, 32);
        v += __shfl_xor(v, 16);
        r[b] = v;
    }

    // lane (g,o) stores batch b = g: one store, all 64 lanes active
    const float vout = (W.g == 0) ? r[0] : (W.g == 1) ? r[1] : (W.g == 2) ? r[2] : r[3];
    W.out[((size_t)(W.g * COUTD + W.o)) * (HWD * HWD) + h * HWD + w] = vout + bv;
    __builtin_amdgcn_sched_barrier(0);
}

__global__ __launch_bounds__(256) void xonv2d_kernel(
    const float* __restrict__ x,
    const float* __restrict__ wts,
    const float* __restrict__ bias,
    float* __restrict__ out)
{
    __shared__ f4 wbuf[WPB][576];    // 9216 B/wave: transpose buffer
    __shared__ f4 xslot[WPB][192];   // 3072 B/wave: x window, zero-padded

    const int lane = threadIdx.x & 63;
    const int wave = threadIdx.x >> 6;

    // XCD banding: XCD k = blockIdx%8 handles sites [k*2048, (k+1)*2048).
    const int xcd = blockIdx.x & 7;
    const int idx = blockIdx.x >> 3;                    // 0..127 within band
    const int site0 = xcd * 2048 + (idx * WPB + wave) * SPW;

    WaveCtx W;
    W.x = x; W.bias = bias; W.out = out;
    W.gw0   = (const f4*)wts + (size_t)site0 * 576;
    W.wbuf  = wbuf[wave];
    W.xslot = xslot[wave];
    W.site0 = site0;
    W.lane  = lane;
    W.o     = lane & 15;
    W.g     = lane >> 4;

    // coop-x decode: element S = lane + 64*j holds the f4 window (cols
    // w-1..w+2) of batch b=S/48, channel c=(S%48)/3, row r=S%3; slot==S.
    #pragma unroll
    for (int j = 0; j < 3; ++j) {
        const int S = lane + 64 * j;
        W.sb[j] = S / 48;
        const int u = S - W.sb[j] * 48;
        W.sc[j] = u / 3;
        W.sr[j] = u - W.sc[j] * 3;
    }

    // ---- prologue: sites 0 and 1 into the two reg buffers ----
    f4 stA[9], stB[9];
    #pragma unroll
    for (int j = 0; j < 9; ++j) stA[j] = W.gw0[j * 64 + lane];
    #pragma unroll
    for (int j = 0; j < 9; ++j) stB[j] = W.gw0[576 + j * 64 + lane];
    __builtin_amdgcn_sched_barrier(0);

    // ---- fully static 4-site pipeline (no runtime-indexed reg arrays) ----
    site_iter(W, 0, stA, true);    // burst -> site 2 into stA
    site_iter(W, 1, stB, true);    // burst -> site 3 into stB
    site_iter(W, 2, stA, false);
    site_iter(W, 3, stB, false);
}

extern "C" void kernel_launch(void* const* d_in, const int* in_sizes, int n_in,
                              void* d_out, int out_size, void* d_ws, size_t ws_size,
                              hipStream_t stream) {
    const float* x    = (const float*)d_in[0];
    const float* wts  = (const float*)d_in[1];
    const float* bias = (const float*)d_in[2];
    float* out = (float*)d_out;

    // 16384 sites / (4 waves * 4 sites) = 1024 blocks of 256 threads.
    // 48KB LDS -> 3 blocks/CU = 12 waves/CU (VGPR ~150-170 matches).
    const int blocks = (HWD * HWD) / (WPB * SPW);
    xonv2d_kernel<<<blocks, WPB * 64, 0, stream>>>(x, wts, bias, out);
}

// Round 5
// 228.983 us; speedup vs baseline: 1.0508x; 1.0193x over previous
//
#include <hip/hip_runtime.h>

// Xonv2D: location-dependent 3x3 conv.
//   x:       (B=4, CIN=16, H=128, W=128)  fp32   -- 4 MB, L2-resident
//   weights: (H, W, COUT=16, CIN=16, 3, 3) fp32  -- 151 MB, read-once stream
//   bias:    (H, W, COUT) fp32
//   out:     (B, COUT, H, W) fp32
//
// V10: run-level amortization -- cut cache-LINE transactions per site ~4x.
//  V8(DMA)=90.3us and V9(reg-staged)=90.7us are IDENTICAL, and V9's VGPR=72
//  proves its staging regs never existed -- staging mechanics are irrelevant.
//  All versions sit at ~2.7 B/cy/CU weight supply while every latency model
//  predicts 5-10us: the serial resource is the CU vmem front end processing
//  CACHE LINES, not HBM. Line audit per site: x coop-gather 4 instr x 64
//  lines (512B lane stride!) = 256 + scattered 4B stores 64 + weights 72 =
//  ~400 lines/site, of which the useful weight stream is only 18%.
//  V10 restructures around line economy:
//   - block = 32 consecutive sites (1 row), 4 waves x 8-site runs.
//   - x staged ONCE per block: 192 rows x 40 floats (cols w0b-4..w0b+35),
//     256 threads, quad-contiguous 64B segments -> ~12 lines/site amortized.
//     One __syncthreads total; afterwards waves are fully independent.
//   - stores batched: per lane 8 run-outputs -> 2 global_store_dwordx4
//     (consecutive w!) = ~8 lines/site (was 64).
//   - bias: 8 dwords/lane prefetched pre-barrier (~0.5 lines/site).
//   - steady loop's ONLY vmem = the 9-DMA weight burst (72 lines/site,
//     8-contiguous-lines per instr = minimal): waits are exact, V8-style
//     single-buffer [wait][frag->reg][lgkm0][issue next DMA][compute].
//  Line budget: ~92/site vs ~400. Prediction: kernel ~25-35us if the
//  line-rate theory holds; 55-75us would instead implicate an outstanding-
//  bytes cap (then: more waves); ~85+ falsifies both.
//  LDS: xs 192*44*4=33.8KB + wbuf 4*9.2KB = 70.6KB -> 2 blocks/CU.
//  Row stride 44 floats: 16B-aligned f4 staging writes, and the 4 g-lanes'
//  read rows (stride 12 rows) land 2-way bank-aliased (free, m136) instead
//  of 4-way at stride 40/16.

#define HWD   128
#define CIND  16
#define COUTD 16
#define SPW   8     // sites per wave (one run, same row)
#define WPB   4     // waves per block -> 32 consecutive sites per block
#define XROWF 44    // xs row stride in floats (16B-aligned, bank-spread)

typedef float f4  __attribute__((ext_vector_type(4)));
typedef float f4u __attribute__((ext_vector_type(4), aligned(4)));

// async DMA: 16B per lane, LDS dest = wave-uniform base + lane*16 (linear).
__device__ __forceinline__ void gload_lds16(const f4* gsrc, f4* ldst) {
    __builtin_amdgcn_global_load_lds(
        (const __attribute__((address_space(1))) unsigned int*)gsrc,
        (__attribute__((address_space(3))) unsigned int*)ldst,
        16, 0, 0);
}

__global__ __launch_bounds__(256) void xonv2d_kernel(
    const float* __restrict__ x,
    const float* __restrict__ wts,
    const float* __restrict__ bias,
    float* __restrict__ out)
{
    __shared__ float xs[192 * XROWF];   // 33792 B: block x slab
    __shared__ f4 wbuf[WPB][576];       // 4 x 9216 B: per-wave weight buffer

    const int tid  = threadIdx.x;
    const int lane = tid & 63;
    const int wv   = tid >> 6;

    // XCD banding: XCD k = blockIdx%8 handles sites [k*2048,(k+1)*2048).
    // Bands are 16 whole rows, so blocks stay row-aligned.
    const int xcd  = blockIdx.x & 7;
    const int idx  = blockIdx.x >> 3;          // 0..63 within band
    const int sblk = xcd * 2048 + idx * 32;    // block's first site
    const int h    = sblk >> 7;
    const int w0b  = sblk & 127;               // 0,32,64,96
    const int w0   = w0b + wv * 8;             // wave's first site col

    const int o  = lane & 15;    // output channel
    const int g  = lane >> 4;    // channel group: c in [4g,4g+4)
    const int c0 = g * 4;

    // ---- coop x stage: 192 rows x 10 f4 (cols w0b-4..w0b+35), 256 thr ----
    // t -> row R = t/10 = (b*16+c)*3 + r, f4 q = t%10, col base cb = w0b-4+4q.
    // OOB (h edge / w edge) f4s are written as zeros: the padding IS the
    // zero-pad of the conv, so compute needs no edge branches at all.
    #pragma unroll
    for (int j = 0; j < 8; ++j) {
        const int t = tid + 256 * j;
        if (t < 1920) {
            const int R = t / 10, q = t - R * 10;
            const int b = R / 48;
            const int u = R - b * 48;
            const int c = u / 3, r = u - c * 3;
            const int hy = h + r - 1;
            const int cb = w0b - 4 + 4 * q;
            f4 v = {0.f, 0.f, 0.f, 0.f};
            if (((unsigned)hy < (unsigned)HWD) & ((unsigned)cb <= (unsigned)(HWD - 4)))
                v = *(const f4u*)(x + ((size_t)(b * CIND + c) * HWD + hy) * HWD + cb);
            *(f4*)&xs[R * XROWF + q * 4] = v;   // ds_write_b128, conflict-free
        }
    }

    // ---- bias prefetch: the run's 8 values per lane (4 lines per wave) ----
    float bvr[SPW];
    #pragma unroll
    for (int s = 0; s < SPW; ++s)
        bvr[s] = bias[(size_t)(sblk + wv * 8 + s) * COUTD + o];

    // ---- first weight DMA; the barrier's drain doubles as its wait ----
    const f4* gw0 = (const f4*)wts + (size_t)(sblk + wv * 8) * 576;
    #pragma unroll
    for (int j = 0; j < 9; ++j)
        gload_lds16(gw0 + j * 64 + lane, &wbuf[wv][j * 64]);

    __syncthreads();   // x slab visible; vmcnt drained (w0 + bias landed)

    f4 rsA, rsB;       // batched run outputs (static element writes)

    #pragma unroll
    for (int s = 0; s < SPW; ++s) {
        // A: weight buffer ready. Only the 9 DMAs are ever outstanding
        //    here -- the wait is exact, nothing else gets drained.
        if (s > 0) asm volatile("s_waitcnt vmcnt(0)" ::: "memory");
        __builtin_amdgcn_sched_barrier(0);

        // B: (o,g) 36-float fragment -> regs; buffer free after lgkm(0).
        f4 wvr[9];
        {
            const f4* lp = &wbuf[wv][o * 36 + g * 9];
            #pragma unroll
            for (int j = 0; j < 9; ++j) wvr[j] = lp[j];   // ds_read_b128
        }
        asm volatile("s_waitcnt lgkmcnt(0)" ::: "memory");
        __builtin_amdgcn_sched_barrier(0);

        // C: next site's DMA into the same buffer; flies across compute.
        if (s + 1 < SPW) {
            const f4* gw = gw0 + (size_t)(s + 1) * 576;
            #pragma unroll
            for (int j = 0; j < 9; ++j)
                gload_lds16(gw + j * 64 + lane, &wbuf[wv][j * 64]);
        }
        __builtin_amdgcn_sched_barrier(0);

        // D: compute site from the x slab (LDS only, lgkm counter only).
        //    col(slot) = w0b-4+slot; window col = w+kw-1 -> slot wv*8+s+3+kw.
        const float* wf = (const float*)wvr;
        const int slot0 = wv * 8 + s + 3;
        float acc[4] = {0.f, 0.f, 0.f, 0.f};
        #pragma unroll
        for (int cc = 0; cc < 4; ++cc) {
            #pragma unroll
            for (int b = 0; b < 4; ++b) {
                #pragma unroll
                for (int r = 0; r < 3; ++r) {
                    const int R = (b * CIND + c0 + cc) * 3 + r;
                    const float* xp = &xs[R * XROWF + slot0];
                    const float* wr = wf + cc * 9 + r * 3;
                    acc[b] = fmaf(xp[0], wr[0], acc[b]);
                    acc[b] = fmaf(xp[1], wr[1], acc[b]);
                    acc[b] = fmaf(xp[2], wr[2], acc[b]);
                }
            }
        }

        // E: butterfly over the 4 c-groups; lane (g,o) keeps batch b=g.
        float rr[4];
        #pragma unroll
        for (int b = 0; b < 4; ++b) {
            float v = acc[b];
            v += __shfl_xor(v, 32);
            v += __shfl_xor(v, 16);
            rr[b] = v;
        }
        const float vout = (g == 0) ? rr[0] : (g == 1) ? rr[1]
                         : (g == 2) ? rr[2] : rr[3];
        const float ov = vout + bvr[s];
        if (s < 4) rsA[s] = ov; else rsB[s - 4] = ov;   // s is static (unrolled)
    }

    // ---- batched store: 8 consecutive w per lane = 2 dwordx4 ----
    float* ob = out + ((size_t)(g * COUTD + o)) * (HWD * HWD) + h * HWD + w0;
    *(f4*)(ob)     = rsA;
    *(f4*)(ob + 4) = rsB;
}

extern "C" void kernel_launch(void* const* d_in, const int* in_sizes, int n_in,
                              void* d_out, int out_size, void* d_ws, size_t ws_size,
                              hipStream_t stream) {
    const float* x    = (const float*)d_in[0];
    const float* wts  = (const float*)d_in[1];
    const float* bias = (const float*)d_in[2];
    float* out = (float*)d_out;

    // 16384 sites / 32 per block = 512 blocks of 256 threads.
    // 70.6KB LDS -> 2 blocks/CU, exactly 512 resident: single round.
    const int blocks = (HWD * HWD) / (WPB * SPW);
    xonv2d_kernel<<<blocks, WPB * 64, 0, stream>>>(x, wts, bias, out);
}